// Round 3
// baseline (635.268 us; speedup 1.0000x reference)
//
#include <hip/hip_runtime.h>

#define B_TOK 32768
#define EDIM 2048
#define RDIM 128
#define NEXP 16

// ---------------------------------------------------------------------------
// Kernel 1: router logits (double acc) + argmax + atomic append to per-expert
// token lists. perm layout: perm[e * B_TOK + slot] = token.
// ---------------------------------------------------------------------------
__global__ __launch_bounds__(256) void k_router(
    const float* __restrict__ rin, const float* __restrict__ rw,
    const float* __restrict__ rb, int* __restrict__ counts,
    int* __restrict__ perm)
{
  // 64 rows x 128 floats, pitch 33 float4 (132 floats) for bank spread
  __shared__ float lds[64 * 132];
  const int t = threadIdx.x;
  const int row0 = blockIdx.x * 64;

  {
    const int r = t >> 2;          // 64 rows, 4 threads each
    const int c0 = t & 3;
    const float4* src = (const float4*)(rin + (size_t)(row0 + r) * RDIM);
    float4* dst = (float4*)lds;
#pragma unroll
    for (int j = 0; j < 8; ++j) {
      const int f4 = c0 + 4 * j;   // 32 float4 per row
      dst[r * 33 + f4] = src[f4];
    }
  }
  __syncthreads();

  if (t < 64) {
    const int token = row0 + t;
    const float4* arow = (const float4*)lds + t * 33;
    double best = -1e300;
    int bi = 0;
#pragma unroll 1
    for (int e = 0; e < NEXP; ++e) {
      const float4* w = (const float4*)(rw + e * RDIM);  // wave-uniform -> s_load
      double s = (double)rb[e];
#pragma unroll
      for (int i4 = 0; i4 < 32; ++i4) {
        const float4 a = arow[i4];
        const float4 ww = w[i4];
        s += (double)a.x * ww.x + (double)a.y * ww.y +
             (double)a.z * ww.z + (double)a.w * ww.w;
      }
      if (s > best) { best = s; bi = e; }   // strict > == first-max tie-break
    }
    const int slot = atomicAdd(&counts[bi], 1);
    perm[bi * B_TOK + slot] = token;
  }
}

// ---------------------------------------------------------------------------
// Kernel 2: per-expert fused l1 GEMM (2048 -> 16) + activation + l2 (30->32)
// + out (32->1) + residual. Block = 64 tokens of ONE expert, 256 threads.
// ---------------------------------------------------------------------------
__global__ __launch_bounds__(256) void k_moe(
    const float* __restrict__ xin, const float* __restrict__ w1,
    const float* __restrict__ b1, const float* __restrict__ w2,
    const float* __restrict__ b2, const float* __restrict__ w3,
    const float* __restrict__ b3, const int* __restrict__ counts,
    const int* __restrict__ perm, float* __restrict__ out)
{
  const int e = blockIdx.y;
  const int n = counts[e];
  const int start = blockIdx.x * 64;
  if (start >= n) return;

  const int t = threadIdx.x;
  __shared__ float a_lds[64 * 132];   // 64 tokens x 128 floats, pitch 132
  __shared__ float c_lds[64 * 17];    // l1c: 64 tokens x 16, pitch 17
  __shared__ int tok_lds[64];

  if (t < 64) {
    const int idx = start + t;
    tok_lds[t] = (idx < n) ? perm[e * B_TOK + idx] : -1;
  }
  __syncthreads();

  const int r = t >> 2;               // staging row (4 threads per row)
  const int c0 = t & 3;
  const int tr = tok_lds[r];
  const float* srcrow = xin + (size_t)(tr < 0 ? 0 : tr) * EDIM;

  const int m = t & 63;               // compute token (lane id)
  const int og = __builtin_amdgcn_readfirstlane(t >> 6);  // wave-uniform o-group
  const float* wbase = w1 + ((size_t)e * 16 + og * 4) * EDIM;

  float acc[4] = {0.f, 0.f, 0.f, 0.f};

  for (int kc = 0; kc < EDIM; kc += 128) {
    __syncthreads();                  // protect a_lds readers from overwrite
    {
      const float4* src = (const float4*)(srcrow + kc);
      float4* dst = (float4*)a_lds;
#pragma unroll
      for (int j = 0; j < 8; ++j) {
        const int f4 = c0 + 4 * j;
        dst[r * 33 + f4] = src[f4];
      }
    }
    __syncthreads();
    const float4* arow = (const float4*)(a_lds) + m * 33;
#pragma unroll
    for (int i4 = 0; i4 < 32; ++i4) {
      const float4 a = arow[i4];
#pragma unroll
      for (int o = 0; o < 4; ++o) {
        const float4 w = *(const float4*)(wbase + (size_t)o * EDIM + kc + i4 * 4);
        acc[o] = fmaf(a.x, w.x, acc[o]);
        acc[o] = fmaf(a.y, w.y, acc[o]);
        acc[o] = fmaf(a.z, w.z, acc[o]);
        acc[o] = fmaf(a.w, w.w, acc[o]);
      }
    }
  }

#pragma unroll
  for (int o = 0; o < 4; ++o)
    c_lds[m * 17 + og * 4 + o] = acc[o] + b1[e * 16 + og * 4 + o];
  __syncthreads();

  if (t < 64 && start + t < n) {
    const int token = tok_lds[t];
    const float* c = &c_lds[t * 17];
    const float xo = c[15];           // raw passthrough (l1x_out)
    float x[30];
#pragma unroll
    for (int j = 0; j < 15; ++j) {
      const float v = c[j];
      x[j] = fminf(v * v * (255.0f / 256.0f), 1.0f);     // sq >= 0 already
      x[j + 15] = fminf(fmaxf(v, 0.0f), 1.0f);
    }
    const float* w2e = w2 + (size_t)e * 32 * 30;          // wave-uniform
    const float* b2e = b2 + e * 32;
    const float* w3e = w3 + e * 32;
    float acc3 = b3[e];
#pragma unroll 1
    for (int o2 = 0; o2 < 32; ++o2) {
      float s = b2e[o2];
#pragma unroll
      for (int i = 0; i < 30; ++i) s = fmaf(x[i], w2e[o2 * 30 + i], s);
      s = fminf(fmaxf(s, 0.0f), 1.0f);
      acc3 = fmaf(s, w3e[o2], acc3);
    }
    out[token] = acc3 + xo;
  }
}

extern "C" void kernel_launch(void* const* d_in, const int* in_sizes, int n_in,
                              void* d_out, int out_size, void* d_ws, size_t ws_size,
                              hipStream_t stream) {
  const float* xin = (const float*)d_in[0];   // expert_input (B, 2048)
  const float* rin = (const float*)d_in[1];   // router_input (B, 128)
  const float* rw  = (const float*)d_in[2];   // router_w (16, 128)
  const float* rb  = (const float*)d_in[3];   // router_b (16)
  const float* w1  = (const float*)d_in[4];   // l1_w (16, 16, 2048)
  const float* b1  = (const float*)d_in[5];   // l1_b (16, 16)
  const float* w2  = (const float*)d_in[6];   // l2_w (16, 32, 30)
  const float* b2  = (const float*)d_in[7];   // l2_b (16, 32)
  const float* w3  = (const float*)d_in[8];   // out_w (16, 1, 32)
  const float* b3  = (const float*)d_in[9];   // out_b (16, 1)
  float* out = (float*)d_out;

  int* counts = (int*)d_ws;                   // [16] (+pad to 64)
  int* perm   = counts + 64;                  // [16 * B_TOK]

  hipMemsetAsync(counts, 0, 64 * sizeof(int), stream);
  k_router<<<dim3(B_TOK / 64), 256, 0, stream>>>(rin, rw, rb, counts, perm);
  k_moe<<<dim3(B_TOK / 64, NEXP), 256, 0, stream>>>(xin, w1, b1, w2, b2, w3, b3,
                                                    counts, perm, out);
}